// Round 3
// baseline (419.074 us; speedup 1.0000x reference)
//
#include <hip/hip_runtime.h>
#include <stdint.h>

typedef float f32x4 __attribute__((ext_vector_type(4)));

#define LOG2E 1.4426950408889634f

__device__ __forceinline__ float rcp_f(float x) { return __builtin_amdgcn_rcpf(x); }
__device__ __forceinline__ float sqrt_f(float x) { return __builtin_amdgcn_sqrtf(x); }
__device__ __forceinline__ float exp2_f(float x) { return __builtin_amdgcn_exp2f(x); }
__device__ __forceinline__ float tanh_fast(float a) {
    // tanh(a) = 1 - 2/(e^{2a}+1); exp2 saturates to 0/inf so tails clamp to -1/+1 exactly
    float e = exp2_f(a * (2.0f * LOG2E));
    return 1.0f - 2.0f * rcp_f(e + 1.0f);
}

struct Params {
    float we0, we1, be, wd0, wd1, bd0, bd1;
    float w1[30], b1[10], w2[20], b20, b21;
};

__device__ __forceinline__ void compute_row(const Params& p, float x0, float x1, float o[8]) {
    float enc = fmaf(x1, p.we1, fmaf(x0, p.we0, p.be));
    float d0  = fmaf(enc, p.wd0, p.bd0);
    float d1  = fmaf(enc, p.wd1, p.bd1);
    float xn  = sqrt_f(fmaf(x1, x1, x0 * x0));
    float dn  = sqrt_f(fmaf(d1, d1, d0 * d0));
    float dot = fmaf(x1, d1, x0 * d0);
    float cosv = dot * rcp_f(fmaxf(xn, 1e-8f) * fmaxf(dn, 1e-8f));
    float e0 = x0 - d0, e1 = x1 - d1;
    float eu = sqrt_f(fmaf(e1, e1, e0 * e0)) * rcp_f(xn);
    float l0 = p.b20, l1 = p.b21;
#pragma unroll
    for (int j = 0; j < 10; ++j) {
        float a = fmaf(enc, p.w1[3*j],
                  fmaf(eu,  p.w1[3*j+1],
                  fmaf(cosv, p.w1[3*j+2], p.b1[j])));
        float h = tanh_fast(a);
        l0 = fmaf(h, p.w2[j],      l0);
        l1 = fmaf(h, p.w2[10 + j], l1);
    }
    float m  = fmaxf(l0, l1);
    float q0 = exp2_f((l0 - m) * LOG2E);
    float q1 = exp2_f((l1 - m) * LOG2E);
    float inv = rcp_f(q0 + q1);
    o[0] = enc; o[1] = d0; o[2] = d1;
    o[3] = enc; o[4] = eu; o[5] = cosv;
    o[6] = q0 * inv; o[7] = q1 * inv;
}

__global__ void __launch_bounds__(256) dagmm_kernel(
    const float* __restrict__ x,
    const float* __restrict__ W_enc,  const float* __restrict__ b_enc,
    const float* __restrict__ W_dec,  const float* __restrict__ b_dec,
    const float* __restrict__ W_est1, const float* __restrict__ b_est1,
    const float* __restrict__ W_est2, const float* __restrict__ b_est2,
    float* __restrict__ out, long long N)
{
    Params p;
    p.we0 = W_enc[0]; p.we1 = W_enc[1]; p.be = b_enc[0];
    p.wd0 = W_dec[0]; p.wd1 = W_dec[1];
    p.bd0 = b_dec[0]; p.bd1 = b_dec[1];
#pragma unroll
    for (int i = 0; i < 30; ++i) p.w1[i] = W_est1[i];
#pragma unroll
    for (int i = 0; i < 10; ++i) p.b1[i] = b_est1[i];
#pragma unroll
    for (int i = 0; i < 20; ++i) p.w2[i] = W_est2[i];
    p.b20 = b_est2[0]; p.b21 = b_est2[1];

    long long t = (long long)blockIdx.x * blockDim.x + threadIdx.x;
    long long row0 = t * 4;
    if (row0 >= N) return;

    float* enc_o = out;
    float* dec_o = out + N;
    float* z_o   = out + 3 * N;
    float* g_o   = out + 6 * N;

    float o[8];
    if (((N & 3LL) == 0) && (row0 + 4 <= N)) {
        const f32x4* xv = (const f32x4*)x;
        f32x4 xa = xv[2 * t];
        f32x4 xb = xv[2 * t + 1];
        float xr[8] = {xa.x, xa.y, xa.z, xa.w, xb.x, xb.y, xb.z, xb.w};
        union { float s[4];  f32x4 v;    } eU;
        union { float s[8];  f32x4 v[2]; } dU;
        union { float s[12]; f32x4 v[3]; } zU;
        union { float s[8];  f32x4 v[2]; } gU;
#pragma unroll
        for (int r = 0; r < 4; ++r) {
            compute_row(p, xr[2*r], xr[2*r + 1], o);
            eU.s[r]       = o[0];
            dU.s[2*r]     = o[1]; dU.s[2*r+1] = o[2];
            zU.s[3*r]     = o[3]; zU.s[3*r+1] = o[4]; zU.s[3*r+2] = o[5];
            gU.s[2*r]     = o[6]; gU.s[2*r+1] = o[7];
        }
        __builtin_nontemporal_store(eU.v,    (f32x4*)enc_o + t);
        __builtin_nontemporal_store(dU.v[0], (f32x4*)dec_o + 2*t);
        __builtin_nontemporal_store(dU.v[1], (f32x4*)dec_o + 2*t + 1);
        __builtin_nontemporal_store(zU.v[0], (f32x4*)z_o + 3*t);
        __builtin_nontemporal_store(zU.v[1], (f32x4*)z_o + 3*t + 1);
        __builtin_nontemporal_store(zU.v[2], (f32x4*)z_o + 3*t + 2);
        __builtin_nontemporal_store(gU.v[0], (f32x4*)g_o + 2*t);
        __builtin_nontemporal_store(gU.v[1], (f32x4*)g_o + 2*t + 1);
    } else {
        long long rend = (row0 + 4 < N) ? (row0 + 4) : N;
        for (long long row = row0; row < rend; ++row) {
            float x0 = x[2*row];
            float x1 = x[2*row + 1];
            compute_row(p, x0, x1, o);
            enc_o[row]     = o[0];
            dec_o[2*row]   = o[1]; dec_o[2*row+1] = o[2];
            z_o[3*row]     = o[3]; z_o[3*row+1]   = o[4]; z_o[3*row+2] = o[5];
            g_o[2*row]     = o[6]; g_o[2*row+1]   = o[7];
        }
    }
}

extern "C" void kernel_launch(void* const* d_in, const int* in_sizes, int n_in,
                              void* d_out, int out_size, void* d_ws, size_t ws_size,
                              hipStream_t stream) {
    long long N = (long long)in_sizes[0] / 2;
    long long nthreads = (N + 3) / 4;
    int block = 256;
    int grid = (int)((nthreads + block - 1) / block);
    dagmm_kernel<<<grid, block, 0, stream>>>(
        (const float*)d_in[0],
        (const float*)d_in[1], (const float*)d_in[2],
        (const float*)d_in[3], (const float*)d_in[4],
        (const float*)d_in[5], (const float*)d_in[6],
        (const float*)d_in[7], (const float*)d_in[8],
        (float*)d_out, N);
}